// Round 6
// baseline (582.911 us; speedup 1.0000x reference)
//
#include <hip/hip_runtime.h>
#include <hip/hip_bf16.h>

typedef unsigned short ushort_t;
typedef __attribute__((ext_vector_type(8))) short short8;
typedef __attribute__((ext_vector_type(4))) float f32x4;
typedef __attribute__((ext_vector_type(4))) unsigned int uint4v;

#define NQ      2048
#define ND      512
#define NDB     100000
#define TOPK    10
#define NCHUNK  49
#define CHUNK_N 2048                  // 16 tiles * 128
#define NPAD    (NCHUNK * CHUNK_N)    // 100352 >= 100000
#define QTILES  (NQ / 128)            // 16
#define NTILES  (CHUNK_N / 128)       // 16
#define NWG     (NCHUNK * QTILES)     // 784 = 8 * 98
#define PERXCD  (NWG / 8)             // 98

// async global->LDS, 16B per lane, wave-uniform LDS base + lane*16
#define GL2LDS(gp, lp) __builtin_amdgcn_global_load_lds(                      \
    (const __attribute__((address_space(1))) void*)(gp),                     \
    (__attribute__((address_space(3))) void*)(lp), 16, 0, 0)

// ---------- fp32 -> bf16 (round to nearest even) ----------
static __device__ inline ushort_t f2bf(float x) {
    unsigned u = __float_as_uint(x);
    unsigned r = (u + 0x7FFFu + ((u >> 16) & 1u)) >> 16;
    return (ushort_t)r;
}

// ---------- row L2-normalize, fp32 -> bf16, one wave per row; zero-fill pad rows ----------
__global__ void normalize_rows(const float* __restrict__ in, ushort_t* __restrict__ out,
                               int nvalid, int ntotal) {
    int row  = blockIdx.x * 4 + (threadIdx.x >> 6);
    int lane = threadIdx.x & 63;
    if (row >= ntotal) return;
    uint4v pk;
    if (row >= nvalid) {
        pk[0] = 0u; pk[1] = 0u; pk[2] = 0u; pk[3] = 0u;
    } else {
        const float4* src = reinterpret_cast<const float4*>(in + (size_t)row * ND);
        float4 v0 = src[lane * 2];
        float4 v1 = src[lane * 2 + 1];
        float s = v0.x*v0.x + v0.y*v0.y + v0.z*v0.z + v0.w*v0.w
                + v1.x*v1.x + v1.y*v1.y + v1.z*v1.z + v1.w*v1.w;
        #pragma unroll
        for (int off = 32; off; off >>= 1) s += __shfl_xor(s, off, 64);
        float r = rsqrtf(s);
        pk[0] = (unsigned)f2bf(v0.x * r) | ((unsigned)f2bf(v0.y * r) << 16);
        pk[1] = (unsigned)f2bf(v0.z * r) | ((unsigned)f2bf(v0.w * r) << 16);
        pk[2] = (unsigned)f2bf(v1.x * r) | ((unsigned)f2bf(v1.y * r) << 16);
        pk[3] = (unsigned)f2bf(v1.z * r) | ((unsigned)f2bf(v1.w * r) << 16);
    }
    *reinterpret_cast<uint4v*>(out + (size_t)row * ND + lane * 8) = pk;
}

__device__ inline void topk_insert(float (&top)[TOPK], float x) {
    #pragma unroll
    for (int i = 0; i < TOPK; ++i) {
        float mx = fmaxf(top[i], x);
        x = fminf(top[i], x);
        top[i] = mx;
    }
}

// ---------- fused GEMM + per-chunk top-10 ----------
// 256 threads, 4 waves; wave wv owns queries [wv*32, wv*32+32) x 128 n per tile.
// A K-panel in registers (loaded once). B triple-buffered in LDS, depth-2
// prefetch, counted s_waitcnt vmcnt(4) (never 0 in steady state) + raw s_barrier.
// SWAPPED mfma(B,A): acc[qs][ns][r] = score[n][q = qs*16+(lane&15)] -> top-10 in regs.
__global__ __launch_bounds__(256, 2)
void knn_chunk(const ushort_t* __restrict__ qb, const ushort_t* __restrict__ dbb,
               float* __restrict__ partial) {
    // XCD-chunked swizzle: co-locate the 16 blocks sharing one B-chunk on one XCD
    const int logical = (blockIdx.x % 8) * PERXCD + blockIdx.x / 8;
    const int qt = logical & (QTILES - 1);
    const int nc = logical >> 4;       // QTILES == 16
    const int t = threadIdx.x, lane = t & 63, wv = t >> 6;

    __shared__ __align__(16) ushort_t Bs[3][128 * 64];   // 48 KB

    // ---- A K-panel in registers: af[qs][kk] (B-operand layout of mfma_16x16x32) ----
    short8 af[2][16];
    {
        const ushort_t* aseg = qb + (size_t)(qt * 128) * ND;
        #pragma unroll
        for (int qs = 0; qs < 2; ++qs) {
            const ushort_t* ap = aseg + (size_t)(wv * 32 + qs * 16 + (lane & 15)) * ND + (lane >> 4) * 8;
            #pragma unroll
            for (int kk = 0; kk < 16; ++kk)
                af[qs][kk] = *reinterpret_cast<const short8*>(ap + kk * 32);
        }
    }

    float top[2][TOPK];
    #pragma unroll
    for (int qs = 0; qs < 2; ++qs)
        #pragma unroll
        for (int i = 0; i < TOPK; ++i) top[qs][i] = -1e30f;

    const size_t nchunkbase = (size_t)nc * CHUNK_N;
    const int cb = wv * 256;          // wave's 16B-chunk base among the tile's 1024 chunks

    // stage one 128x64 B K-slice into dst; inverse-swizzled global source + linear LDS
    auto stageB = [&](size_t rowbase, int kbase, ushort_t* dst) {
        const ushort_t* bseg = dbb + rowbase * ND;
        #pragma unroll
        for (int i = 0; i < 4; ++i) {
            const int cid = cb + i * 64 + lane;
            const int row = cid >> 3;
            const int c   = (cid & 7) ^ (row & 7);
            GL2LDS(bseg + (size_t)row * ND + kbase + c * 8, dst + (cb + i * 64) * 8);
        }
    };

    ushort_t* r0 = &Bs[0][0];
    ushort_t* r1 = &Bs[1][0];
    ushort_t* r2 = &Bs[2][0];

    // prologue: stage steps 0 and 1 (depth 2)
    stageB(nchunkbase, 0, r0);
    stageB(nchunkbase, 64, r1);

    #pragma unroll 1
    for (int nt = 0; nt < NTILES; ++nt) {
        f32x4 acc[2][8];
        #pragma unroll
        for (int a = 0; a < 2; ++a)
            #pragma unroll
            for (int b = 0; b < 8; ++b)
                acc[a][b] = (f32x4){0.f, 0.f, 0.f, 0.f};

        #pragma unroll
        for (int ks = 0; ks < 8; ++ks) {
            // counted wait: leave next step's 4 loads in flight; full drain only at the very end
            if (ks == 7 && nt == NTILES - 1) {
                asm volatile("s_waitcnt vmcnt(0)" ::: "memory");
            } else {
                asm volatile("s_waitcnt vmcnt(4)" ::: "memory");
            }
            __builtin_amdgcn_s_barrier();
            asm volatile("" ::: "memory");      // fence: no LDS reads hoist above barrier

            // issue stage for step g+2 (depth-2 prefetch)
            ushort_t* tgt = ((ks + 2) % 3 == 0) ? r0 : ((ks + 2) % 3 == 1) ? r1 : r2;
            if (ks <= 5) {
                stageB(nchunkbase + nt * 128, (ks + 2) * 64, tgt);
            } else if (nt + 1 < NTILES) {
                stageB(nchunkbase + (nt + 1) * 128, (ks - 6) * 64, tgt);
            }

            const ushort_t* cur = (ks % 3 == 0) ? r0 : (ks % 3 == 1) ? r1 : r2;
            #pragma unroll
            for (int ksub = 0; ksub < 2; ++ksub) {
                const int j0 = (ksub * 4 + (lane >> 4)) ^ (lane & 7);   // swizzled 16B-chunk in row
                short8 bf[8];
                #pragma unroll
                for (int ns = 0; ns < 8; ++ns)
                    bf[ns] = *reinterpret_cast<const short8*>(cur + (ns * 16 + (lane & 15)) * 64 + j0 * 8);
                __builtin_amdgcn_s_setprio(1);
                #pragma unroll
                for (int qs = 0; qs < 2; ++qs)
                    #pragma unroll
                    for (int ns = 0; ns < 8; ++ns)
                        acc[qs][ns] = __builtin_amdgcn_mfma_f32_16x16x32_bf16(bf[ns], af[qs][ks * 2 + ksub], acc[qs][ns], 0, 0, 0);
                __builtin_amdgcn_s_setprio(0);
            }
        }
        // rotate buffers: 8 steps == 2 (mod 3)
        { ushort_t* n0 = r2; ushort_t* n1 = r0; ushort_t* n2 = r1; r0 = n0; r1 = n1; r2 = n2; }

        // in-register selection; prefetched stages keep flying underneath
        #pragma unroll
        for (int qs = 0; qs < 2; ++qs) {
            float m = -1e30f;
            #pragma unroll
            for (int ns = 0; ns < 8; ++ns) {
                float m0 = fmaxf(fmaxf(acc[qs][ns][0], acc[qs][ns][1]),
                                 fmaxf(acc[qs][ns][2], acc[qs][ns][3]));
                m = fmaxf(m, m0);
            }
            if (m > top[qs][TOPK - 1]) {
                #pragma unroll
                for (int ns = 0; ns < 8; ++ns)
                    #pragma unroll
                    for (int r = 0; r < 4; ++r) {
                        float v = acc[qs][ns][r];
                        if (v > top[qs][TOPK - 1]) topk_insert(top[qs], v);
                    }
            }
        }
    }

    // butterfly merge across the 4 lanes sharing each query (lane ^ 16, lane ^ 32)
    #pragma unroll
    for (int qs = 0; qs < 2; ++qs) {
        #pragma unroll
        for (int step = 16; step <= 32; step <<= 1) {
            float other[TOPK];
            #pragma unroll
            for (int i = 0; i < TOPK; ++i) other[i] = __shfl_xor(top[qs][i], step, 64);
            #pragma unroll
            for (int i = 0; i < TOPK; ++i)
                if (other[i] > top[qs][TOPK - 1]) topk_insert(top[qs], other[i]);
        }
    }

    // lanes 0..15 hold the final per-query top-10 for q = qt*128 + wv*32 + qs*16 + lane
    if ((lane >> 4) == 0) {
        #pragma unroll
        for (int qs = 0; qs < 2; ++qs) {
            const int q = qt * 128 + wv * 32 + qs * 16 + lane;
            float* dst = partial + ((size_t)nc * NQ + q) * TOPK;
            #pragma unroll
            for (int i = 0; i < TOPK; ++i) dst[i] = top[qs][i];
        }
    }
}

// ---------- merge chunks, emit k-th squared distance ----------
__global__ void final_merge(const float* __restrict__ partial, float* __restrict__ out) {
    int q = blockIdx.x * 256 + threadIdx.x;
    if (q >= NQ) return;
    float top[TOPK];
    #pragma unroll
    for (int i = 0; i < TOPK; ++i) top[i] = -1e30f;
    for (int c = 0; c < NCHUNK; ++c) {
        const float* p = partial + ((size_t)c * NQ + q) * TOPK;
        #pragma unroll
        for (int i = 0; i < TOPK; ++i) {
            float x = p[i];
            if (x > top[TOPK - 1]) topk_insert(top, x);
        }
    }
    out[q] = 2.0f - 2.0f * top[TOPK - 1];
}

extern "C" void kernel_launch(void* const* d_in, const int* in_sizes, int n_in,
                              void* d_out, int out_size, void* d_ws, size_t ws_size,
                              hipStream_t stream) {
    const float* features = (const float*)d_in[0];
    const float* dbf      = (const float*)d_in[2];
    float* out = (float*)d_out;

    ushort_t* dbb = (ushort_t*)d_ws;                         // [NPAD][512] bf16   ~102.8 MB
    ushort_t* qbn = dbb + (size_t)NPAD * ND;                 // [2048][512] bf16   ~2 MB
    float* partial = (float*)(qbn + (size_t)NQ * ND);        // [NCHUNK][2048][10] ~4.0 MB

    normalize_rows<<<NPAD / 4, 256, 0, stream>>>(dbf, dbb, NDB, NPAD);
    normalize_rows<<<NQ / 4, 256, 0, stream>>>(features, qbn, NQ, NQ);
    knn_chunk<<<NWG, 256, 0, stream>>>(qbn, dbb, partial);
    final_merge<<<(NQ + 255) / 256, 256, 0, stream>>>(partial, out);
}

// Round 7
// 565.052 us; speedup vs baseline: 1.0316x; 1.0316x over previous
//
#include <hip/hip_runtime.h>
#include <hip/hip_bf16.h>

typedef unsigned short ushort_t;
typedef __attribute__((ext_vector_type(8))) short short8;
typedef __attribute__((ext_vector_type(16))) float f32x16;
typedef __attribute__((ext_vector_type(4))) unsigned int uint4v;

#define NQ      2048
#define ND      512
#define NDB     100000
#define TOPK    10
#define NCHUNK  49
#define CHUNK_N 2048                  // 16 tiles * 128
#define NPAD    (NCHUNK * CHUNK_N)    // 100352 >= 100000
#define QTILES  (NQ / 128)            // 16
#define NTILES  (CHUNK_N / 128)       // 16
#define NWG     (NCHUNK * QTILES)     // 784 = 8 * 98
#define PERXCD  (NWG / 8)             // 98

// async global->LDS, 16B per lane, wave-uniform LDS base + lane*16
#define GL2LDS(gp, lp) __builtin_amdgcn_global_load_lds(                      \
    (const __attribute__((address_space(1))) void*)(gp),                     \
    (__attribute__((address_space(3))) void*)(lp), 16, 0, 0)

// ---------- fp32 -> bf16 (round to nearest even) ----------
static __device__ inline ushort_t f2bf(float x) {
    unsigned u = __float_as_uint(x);
    unsigned r = (u + 0x7FFFu + ((u >> 16) & 1u)) >> 16;
    return (ushort_t)r;
}

// ---------- row L2-normalize, fp32 -> bf16, one wave per row; zero-fill pad rows ----------
__global__ void normalize_rows(const float* __restrict__ in, ushort_t* __restrict__ out,
                               int nvalid, int ntotal) {
    int row  = blockIdx.x * 4 + (threadIdx.x >> 6);
    int lane = threadIdx.x & 63;
    if (row >= ntotal) return;
    uint4v pk;
    if (row >= nvalid) {
        pk[0] = 0u; pk[1] = 0u; pk[2] = 0u; pk[3] = 0u;
    } else {
        const float4* src = reinterpret_cast<const float4*>(in + (size_t)row * ND);
        float4 v0 = src[lane * 2];
        float4 v1 = src[lane * 2 + 1];
        float s = v0.x*v0.x + v0.y*v0.y + v0.z*v0.z + v0.w*v0.w
                + v1.x*v1.x + v1.y*v1.y + v1.z*v1.z + v1.w*v1.w;
        #pragma unroll
        for (int off = 32; off; off >>= 1) s += __shfl_xor(s, off, 64);
        float r = rsqrtf(s);
        pk[0] = (unsigned)f2bf(v0.x * r) | ((unsigned)f2bf(v0.y * r) << 16);
        pk[1] = (unsigned)f2bf(v0.z * r) | ((unsigned)f2bf(v0.w * r) << 16);
        pk[2] = (unsigned)f2bf(v1.x * r) | ((unsigned)f2bf(v1.y * r) << 16);
        pk[3] = (unsigned)f2bf(v1.z * r) | ((unsigned)f2bf(v1.w * r) << 16);
    }
    *reinterpret_cast<uint4v*>(out + (size_t)row * ND + lane * 8) = pk;
}

__device__ inline void topk_insert(float (&top)[TOPK], float x) {
    #pragma unroll
    for (int i = 0; i < TOPK; ++i) {
        float mx = fmaxf(top[i], x);
        x = fminf(top[i], x);
        top[i] = mx;
    }
}

// ---------- fused GEMM + per-chunk top-10, 32x32x16 MFMA, phase-interleaved ----------
// 256 threads, 4 waves; wave wv owns queries [wv*32, wv*32+32) x 128 n per tile.
// A K-panel in registers (af[32], q = lane&31). B triple-buffered in LDS,
// depth-2 prefetch, counted vmcnt. K-step split into 4 phases:
//   {4 ds_read | stage-issue | barrier | setprio + 4 MFMA + setprio | barrier}
// SWAPPED mfma(B,A): D[n][q]; q = lane&31 per thread -> single top[10] per thread.
__global__ __launch_bounds__(256, 2)
void knn_chunk(const ushort_t* __restrict__ qb, const ushort_t* __restrict__ dbb,
               float* __restrict__ partial) {
    // XCD-chunked swizzle: co-locate the 16 blocks sharing one B-chunk on one XCD
    const int logical = (blockIdx.x % 8) * PERXCD + blockIdx.x / 8;
    const int qt = logical & (QTILES - 1);
    const int nc = logical >> 4;       // QTILES == 16
    const int t = threadIdx.x, lane = t & 63, wv = t >> 6;

    __shared__ __align__(16) ushort_t Bs[3][128 * 64];   // 48 KB

    // ---- A K-panel in registers: af[f], f = K/16 slice.
    // B-operand layout of mfma_32x32x16: col(q) = lane&31, k = f*16 + (lane>>5)*8 + j
    short8 af[32];
    {
        const ushort_t* ap = qb + (size_t)(qt * 128 + wv * 32 + (lane & 31)) * ND + (lane >> 5) * 8;
        #pragma unroll
        for (int f = 0; f < 32; ++f)
            af[f] = *reinterpret_cast<const short8*>(ap + f * 16);
    }

    float top[TOPK];
    #pragma unroll
    for (int i = 0; i < TOPK; ++i) top[i] = -1e30f;

    const size_t nchunkbase = (size_t)nc * CHUNK_N;
    const int cb = wv * 256;          // wave's 16B-chunk base among the tile's 1024 chunks

    // stage one 128x64 B K-slice into dst; inverse-swizzled global source + linear LDS
    auto stageB = [&](size_t rowbase, int kbase, ushort_t* dst) {
        const ushort_t* bseg = dbb + rowbase * ND;
        #pragma unroll
        for (int i = 0; i < 4; ++i) {
            const int cid = cb + i * 64 + lane;
            const int row = cid >> 3;
            const int c   = (cid & 7) ^ (row & 7);
            GL2LDS(bseg + (size_t)row * ND + kbase + c * 8, dst + (cb + i * 64) * 8);
        }
    };

    ushort_t* r0 = &Bs[0][0];
    ushort_t* r1 = &Bs[1][0];
    ushort_t* r2 = &Bs[2][0];

    // prologue: stage steps 0 and 1 (depth 2)
    stageB(nchunkbase, 0, r0);
    stageB(nchunkbase, 64, r1);

    #pragma unroll 1
    for (int nt = 0; nt < NTILES; ++nt) {
        f32x16 acc[4];
        #pragma unroll
        for (int ns = 0; ns < 4; ++ns)
            #pragma unroll
            for (int r = 0; r < 16; ++r) acc[ns][r] = 0.f;

        #pragma unroll
        for (int ks = 0; ks < 8; ++ks) {
            // counted wait: current buffer's 4 loads complete; deeper prefetch stays in flight
            if (ks == 7 && nt == NTILES - 1) {
                asm volatile("s_waitcnt vmcnt(0)" ::: "memory");
            } else {
                asm volatile("s_waitcnt vmcnt(4)" ::: "memory");
            }
            __builtin_amdgcn_s_barrier();

            ushort_t* tgt = ((ks + 2) % 3 == 0) ? r0 : ((ks + 2) % 3 == 1) ? r1 : r2;
            const ushort_t* cur = (ks % 3 == 0) ? r0 : (ks % 3 == 1) ? r1 : r2;

            // 4 phases: {ds_read slice p | stage share | barrier | MFMA p | barrier}
            #pragma unroll
            for (int p = 0; p < 4; ++p) {
                short8 bf[4];
                #pragma unroll
                for (int ns = 0; ns < 4; ++ns) {
                    const int row = ns * 32 + (lane & 31);
                    const int j   = p * 2 + (lane >> 5);
                    bf[ns] = *reinterpret_cast<const short8*>(cur + row * 64 + ((j ^ (row & 7)) * 8));
                }
                if (p == 0) {          // issue depth-2 stage once per K-step
                    if (ks <= 5)                stageB(nchunkbase + nt * 128, (ks + 2) * 64, tgt);
                    else if (nt + 1 < NTILES)   stageB(nchunkbase + (nt + 1) * 128, (ks - 6) * 64, tgt);
                }
                __builtin_amdgcn_s_barrier();
                __builtin_amdgcn_s_setprio(1);
                #pragma unroll
                for (int ns = 0; ns < 4; ++ns)
                    acc[ns] = __builtin_amdgcn_mfma_f32_32x32x16_bf16(bf[ns], af[ks * 4 + p], acc[ns], 0, 0, 0);
                __builtin_amdgcn_s_setprio(0);
                __builtin_amdgcn_s_barrier();
            }
        }
        // rotate buffers: 8 steps == 2 (mod 3)
        { ushort_t* n0 = r2; ushort_t* n1 = r0; ushort_t* n2 = r1; r0 = n0; r1 = n1; r2 = n2; }

        // in-register selection: 64 candidates for this thread's single query (q = lane&31)
        #pragma unroll
        for (int ns = 0; ns < 4; ++ns) {
            float m = -1e30f;
            #pragma unroll
            for (int r = 0; r < 16; ++r) m = fmaxf(m, acc[ns][r]);
            if (m > top[TOPK - 1]) {
                #pragma unroll
                for (int r = 0; r < 16; ++r) {
                    float v = acc[ns][r];
                    if (v > top[TOPK - 1]) topk_insert(top, v);
                }
            }
        }
    }

    // merge the 2 lanes sharing each query (lane ^ 32)
    {
        float other[TOPK];
        #pragma unroll
        for (int i = 0; i < TOPK; ++i) other[i] = __shfl_xor(top[i], 32, 64);
        #pragma unroll
        for (int i = 0; i < TOPK; ++i)
            if (other[i] > top[TOPK - 1]) topk_insert(top, other[i]);
    }

    // lanes 0..31 hold the final per-query top-10 for q = qt*128 + wv*32 + lane
    if (lane < 32) {
        const int q = qt * 128 + wv * 32 + lane;
        float* dst = partial + ((size_t)nc * NQ + q) * TOPK;
        #pragma unroll
        for (int i = 0; i < TOPK; ++i) dst[i] = top[i];
    }
}

// ---------- merge chunks, emit k-th squared distance ----------
__global__ void final_merge(const float* __restrict__ partial, float* __restrict__ out) {
    int q = blockIdx.x * 256 + threadIdx.x;
    if (q >= NQ) return;
    float top[TOPK];
    #pragma unroll
    for (int i = 0; i < TOPK; ++i) top[i] = -1e30f;
    for (int c = 0; c < NCHUNK; ++c) {
        const float* p = partial + ((size_t)c * NQ + q) * TOPK;
        #pragma unroll
        for (int i = 0; i < TOPK; ++i) {
            float x = p[i];
            if (x > top[TOPK - 1]) topk_insert(top, x);
        }
    }
    out[q] = 2.0f - 2.0f * top[TOPK - 1];
}

extern "C" void kernel_launch(void* const* d_in, const int* in_sizes, int n_in,
                              void* d_out, int out_size, void* d_ws, size_t ws_size,
                              hipStream_t stream) {
    const float* features = (const float*)d_in[0];
    const float* dbf      = (const float*)d_in[2];
    float* out = (float*)d_out;

    ushort_t* dbb = (ushort_t*)d_ws;                         // [NPAD][512] bf16   ~102.8 MB
    ushort_t* qbn = dbb + (size_t)NPAD * ND;                 // [2048][512] bf16   ~2 MB
    float* partial = (float*)(qbn + (size_t)NQ * ND);        // [NCHUNK][2048][10] ~4.0 MB

    normalize_rows<<<NPAD / 4, 256, 0, stream>>>(dbf, dbb, NDB, NPAD);
    normalize_rows<<<NQ / 4, 256, 0, stream>>>(features, qbn, NQ, NQ);
    knn_chunk<<<NWG, 256, 0, stream>>>(qbn, dbb, partial);
    final_merge<<<(NQ + 255) / 256, 256, 0, stream>>>(partial, out);
}